// Round 1
// baseline (4823.658 us; speedup 1.0000x reference)
//
#include <hip/hip_runtime.h>

constexpr int N = 8192;
constexpr int D = 256;

__device__ __forceinline__ const float4* f4c(const float* p) { return reinterpret_cast<const float4*>(p); }
__device__ __forceinline__ float4* f4(float* p) { return reinterpret_cast<float4*>(p); }

// out[i] = dot(X[i,:], v)   — one wave (64 lanes x float4) per row, D=256
__global__ __launch_bounds__(256) void rowdot_kernel(const float* __restrict__ X,
                                                     const float* __restrict__ v,
                                                     float* __restrict__ out) {
    int lane = threadIdx.x & 63;
    int row = blockIdx.x * 4 + (threadIdx.x >> 6);
    float4 a = f4c(X + (size_t)row * D)[lane];
    float4 b = f4c(v)[lane];
    float s = a.x * b.x + a.y * b.y + a.z * b.z + a.w * b.w;
#pragma unroll
    for (int off = 32; off > 0; off >>= 1) s += __shfl_down(s, off);
    if (lane == 0) out[row] = s;
}

// C[M x 256] = A[M x 256] @ W[256 x 256], all row-major. 64x64 tile, 4x4 micro.
__global__ __launch_bounds__(256) void gemm_nk256_kernel(const float* __restrict__ A,
                                                         const float* __restrict__ W,
                                                         float* __restrict__ C) {
    __shared__ float As[16][68];
    __shared__ float Bs[16][68];
    int t = threadIdx.x;
    int tx = t & 15, ty = t >> 4;
    int j0 = blockIdx.x * 64;
    int i0 = blockIdx.y * 64;
    float acc[4][4] = {};
    for (int k0 = 0; k0 < 256; k0 += 16) {
        {
            int m = t >> 2, k4 = (t & 3) * 4;
            float4 a = *f4c(A + (size_t)(i0 + m) * D + k0 + k4);
            As[k4 + 0][m] = a.x; As[k4 + 1][m] = a.y; As[k4 + 2][m] = a.z; As[k4 + 3][m] = a.w;
            int kk = t >> 4, c = (t & 15) * 4;
            *f4(&Bs[kk][c]) = *f4c(W + (size_t)(k0 + kk) * D + j0 + c);
        }
        __syncthreads();
#pragma unroll
        for (int kk = 0; kk < 16; kk++) {
            float4 av = *f4c(&As[kk][ty * 4]);
            float4 bv = *f4c(&Bs[kk][tx * 4]);
            float a[4] = {av.x, av.y, av.z, av.w};
            float b[4] = {bv.x, bv.y, bv.z, bv.w};
#pragma unroll
            for (int r = 0; r < 4; r++)
#pragma unroll
                for (int c = 0; c < 4; c++) acc[r][c] = fmaf(a[r], b[c], acc[r][c]);
        }
        __syncthreads();
    }
#pragma unroll
    for (int r = 0; r < 4; r++) {
        float4 o = {acc[r][0], acc[r][1], acc[r][2], acc[r][3]};
        *f4(C + (size_t)(i0 + ty * 4 + r) * D + j0 + tx * 4) = o;
    }
}

// newX = leakyrelu(A1@W1 + A2@W2), all [N x 256] / [256 x 256] row-major.
__global__ __launch_bounds__(256) void update_kernel(const float* __restrict__ A1,
                                                     const float* __restrict__ W1,
                                                     const float* __restrict__ A2,
                                                     const float* __restrict__ W2,
                                                     float* __restrict__ C) {
    __shared__ float As[16][68];
    __shared__ float Bs[16][68];
    int t = threadIdx.x;
    int tx = t & 15, ty = t >> 4;
    int j0 = blockIdx.x * 64;
    int i0 = blockIdx.y * 64;
    float acc[4][4] = {};
#pragma unroll 1
    for (int pass = 0; pass < 2; pass++) {
        const float* Ap = pass ? A2 : A1;
        const float* Wp = pass ? W2 : W1;
        for (int k0 = 0; k0 < 256; k0 += 16) {
            {
                int m = t >> 2, k4 = (t & 3) * 4;
                float4 a = *f4c(Ap + (size_t)(i0 + m) * D + k0 + k4);
                As[k4 + 0][m] = a.x; As[k4 + 1][m] = a.y; As[k4 + 2][m] = a.z; As[k4 + 3][m] = a.w;
                int kk = t >> 4, c = (t & 15) * 4;
                *f4(&Bs[kk][c]) = *f4c(Wp + (size_t)(k0 + kk) * D + j0 + c);
            }
            __syncthreads();
#pragma unroll
            for (int kk = 0; kk < 16; kk++) {
                float4 av = *f4c(&As[kk][ty * 4]);
                float4 bv = *f4c(&Bs[kk][tx * 4]);
                float a[4] = {av.x, av.y, av.z, av.w};
                float b[4] = {bv.x, bv.y, bv.z, bv.w};
#pragma unroll
                for (int r = 0; r < 4; r++)
#pragma unroll
                    for (int c = 0; c < 4; c++) acc[r][c] = fmaf(a[r], b[c], acc[r][c]);
            }
            __syncthreads();
        }
    }
#pragma unroll
    for (int r = 0; r < 4; r++) {
        float o[4];
#pragma unroll
        for (int c = 0; c < 4; c++) {
            float x = acc[r][c];
            o[c] = x >= 0.f ? x : 0.1f * x;
        }
        float4 ov = {o[0], o[1], o[2], o[3]};
        *f4(C + (size_t)(i0 + ty * 4 + r) * D + j0 + tx * 4) = ov;
    }
}

// alpha[i,j] = sum_d Z[i,d]*Dp[j,d] + bh[i] + bd[j]   (A @ B^T, K=256)
// 128x128 tile, 8x8 micro, BK=32
__global__ __launch_bounds__(256) void logits_kernel(const float* __restrict__ Z,
                                                     const float* __restrict__ Dp,
                                                     const float* __restrict__ bh,
                                                     const float* __restrict__ bd,
                                                     float* __restrict__ alpha) {
    __shared__ float As[32][132];
    __shared__ float Bs[32][132];
    int t = threadIdx.x;
    int tx = t & 15, ty = t >> 4;
    int j0 = blockIdx.x * 128;
    int i0 = blockIdx.y * 128;
    float acc[8][8] = {};
    for (int k0 = 0; k0 < 256; k0 += 32) {
#pragma unroll
        for (int r = 0; r < 4; r++) {
            int fid = r * 256 + t;
            int m = fid >> 3, k4 = (fid & 7) * 4;
            float4 a = *f4c(Z + (size_t)(i0 + m) * D + k0 + k4);
            As[k4 + 0][m] = a.x; As[k4 + 1][m] = a.y; As[k4 + 2][m] = a.z; As[k4 + 3][m] = a.w;
            float4 b = *f4c(Dp + (size_t)(j0 + m) * D + k0 + k4);
            Bs[k4 + 0][m] = b.x; Bs[k4 + 1][m] = b.y; Bs[k4 + 2][m] = b.z; Bs[k4 + 3][m] = b.w;
        }
        __syncthreads();
#pragma unroll 4
        for (int kk = 0; kk < 32; kk++) {
            float4 a0 = *f4c(&As[kk][ty * 8]);
            float4 a1 = *f4c(&As[kk][ty * 8 + 4]);
            float4 b0 = *f4c(&Bs[kk][tx * 8]);
            float4 b1 = *f4c(&Bs[kk][tx * 8 + 4]);
            float a[8] = {a0.x, a0.y, a0.z, a0.w, a1.x, a1.y, a1.z, a1.w};
            float b[8] = {b0.x, b0.y, b0.z, b0.w, b1.x, b1.y, b1.z, b1.w};
#pragma unroll
            for (int r = 0; r < 8; r++)
#pragma unroll
                for (int c = 0; c < 8; c++) acc[r][c] = fmaf(a[r], b[c], acc[r][c]);
        }
        __syncthreads();
    }
    float4 bd0 = *f4c(bd + j0 + tx * 8);
    float4 bd1 = *f4c(bd + j0 + tx * 8 + 4);
#pragma unroll
    for (int r = 0; r < 8; r++) {
        float bhr = bh[i0 + ty * 8 + r];
        float4 o0 = {acc[r][0] + bhr + bd0.x, acc[r][1] + bhr + bd0.y,
                     acc[r][2] + bhr + bd0.z, acc[r][3] + bhr + bd0.w};
        float4 o1 = {acc[r][4] + bhr + bd1.x, acc[r][5] + bhr + bd1.y,
                     acc[r][6] + bhr + bd1.z, acc[r][7] + bhr + bd1.w};
        float* orow = alpha + (size_t)(i0 + ty * 8 + r) * N + j0 + tx * 8;
        f4(orow)[0] = o0;
        f4(orow)[1] = o1;
    }
}

// in-place row softmax, one block per row (8192 floats in registers)
__global__ __launch_bounds__(256) void softmax_kernel(float* __restrict__ alpha) {
    int row = blockIdx.x;
    int t = threadIdx.x;
    float4* rp = f4(alpha + (size_t)row * N);
    float4 v[8];
    float m = -3.4e38f;
#pragma unroll
    for (int i = 0; i < 8; i++) {
        v[i] = rp[i * 256 + t];
        m = fmaxf(m, fmaxf(fmaxf(v[i].x, v[i].y), fmaxf(v[i].z, v[i].w)));
    }
    __shared__ float red[8];
#pragma unroll
    for (int off = 32; off > 0; off >>= 1) m = fmaxf(m, __shfl_xor(m, off));
    if ((t & 63) == 0) red[t >> 6] = m;
    __syncthreads();
    m = fmaxf(fmaxf(red[0], red[1]), fmaxf(red[2], red[3]));
    float s = 0.f;
#pragma unroll
    for (int i = 0; i < 8; i++) {
        v[i].x = __expf(v[i].x - m);
        v[i].y = __expf(v[i].y - m);
        v[i].z = __expf(v[i].z - m);
        v[i].w = __expf(v[i].w - m);
        s += v[i].x + v[i].y + v[i].z + v[i].w;
    }
#pragma unroll
    for (int off = 32; off > 0; off >>= 1) s += __shfl_xor(s, off);
    if ((t & 63) == 0) red[4 + (t >> 6)] = s;
    __syncthreads();
    s = red[4] + red[5] + red[6] + red[7];
    float inv = 1.f / s;
#pragma unroll
    for (int i = 0; i < 8; i++) {
        v[i].x *= inv; v[i].y *= inv; v[i].z *= inv; v[i].w *= inv;
        rp[i * 256 + t] = v[i];
    }
}

__global__ __launch_bounds__(256) void diag_kernel(const float* __restrict__ alpha,
                                                   float* __restrict__ da) {
    int i = blockIdx.x * 256 + threadIdx.x;
    da[i] = alpha[(size_t)i * N + i];
}

// S = alpha @ X  (z=0)  or  T = alpha^T @ X (z=1); X = [H | Dp] logical N x 512.
// blockIdx.x selects column half (0:H, 1:Dp). 128x256 tile, 8x8 micro, BK=16, 512 thr.
__global__ __launch_bounds__(512) void agg_kernel(const float* __restrict__ alpha,
                                                  const float* __restrict__ H,
                                                  const float* __restrict__ Dp,
                                                  float* __restrict__ S,
                                                  float* __restrict__ T) {
    const int cb = blockIdx.x;
    const int i0 = blockIdx.y * 128;
    const int trans = blockIdx.z;
    const float* B = cb ? Dp : H;
    float* out = trans ? T : S;

    __shared__ float As[16][132];
    __shared__ float Bs[16][264];

    int t = threadIdx.x;
    int tx = t & 31, ty = t >> 5;
    float acc[8][8] = {};

    for (int k0 = 0; k0 < N; k0 += 16) {
        if (!trans) {
            int m = t >> 2, k4 = (t & 3) * 4;
            float4 a = *f4c(alpha + (size_t)(i0 + m) * N + k0 + k4);
            As[k4 + 0][m] = a.x; As[k4 + 1][m] = a.y; As[k4 + 2][m] = a.z; As[k4 + 3][m] = a.w;
        } else {
            int kk = t >> 5, c = (t & 31) * 4;
            float4 a = *f4c(alpha + (size_t)(k0 + kk) * N + i0 + c);
            *f4(&As[kk][c]) = a;
        }
        {
            int kk = t >> 5, c = (t & 31) * 8;
            const float* src = B + (size_t)(k0 + kk) * D + c;
            *f4(&Bs[kk][c]) = *f4c(src);
            *f4(&Bs[kk][c + 4]) = *f4c(src + 4);
        }
        __syncthreads();
#pragma unroll 4
        for (int kk = 0; kk < 16; kk++) {
            float4 a0 = *f4c(&As[kk][ty * 8]);
            float4 a1 = *f4c(&As[kk][ty * 8 + 4]);
            float4 b0 = *f4c(&Bs[kk][tx * 8]);
            float4 b1 = *f4c(&Bs[kk][tx * 8 + 4]);
            float a[8] = {a0.x, a0.y, a0.z, a0.w, a1.x, a1.y, a1.z, a1.w};
            float b[8] = {b0.x, b0.y, b0.z, b0.w, b1.x, b1.y, b1.z, b1.w};
#pragma unroll
            for (int r = 0; r < 8; r++)
#pragma unroll
                for (int c = 0; c < 8; c++) acc[r][c] = fmaf(a[r], b[c], acc[r][c]);
        }
        __syncthreads();
    }
#pragma unroll
    for (int r = 0; r < 8; r++) {
        float4 o0 = {acc[r][0], acc[r][1], acc[r][2], acc[r][3]};
        float4 o1 = {acc[r][4], acc[r][5], acc[r][6], acc[r][7]};
        float* orow = out + (size_t)(i0 + ty * 8 + r) * (2 * D) + cb * D + tx * 8;
        f4(orow)[0] = o0;
        f4(orow)[1] = o1;
    }
}

// hagg = T[:, :D] + S[:, D:] - da*(H+Dp);  dagg = S[:, :D] + T[:, D:] - da*(H+Dp)
__global__ __launch_bounds__(256) void combine_kernel(const float* __restrict__ S,
                                                      const float* __restrict__ T,
                                                      const float* __restrict__ da,
                                                      const float* __restrict__ H,
                                                      const float* __restrict__ Dp,
                                                      float* __restrict__ hagg,
                                                      float* __restrict__ dagg) {
    int gid = blockIdx.x * 256 + threadIdx.x;  // N*D/4 total
    int i = gid >> 6;
    int d4 = (gid & 63) * 4;
    float a = da[i];
    float4 sH = *f4c(S + (size_t)i * (2 * D) + d4);
    float4 sD = *f4c(S + (size_t)i * (2 * D) + D + d4);
    float4 tH = *f4c(T + (size_t)i * (2 * D) + d4);
    float4 tD = *f4c(T + (size_t)i * (2 * D) + D + d4);
    float4 h = *f4c(H + (size_t)i * D + d4);
    float4 dp = *f4c(Dp + (size_t)i * D + d4);
    float4 hd = {h.x + dp.x, h.y + dp.y, h.z + dp.z, h.w + dp.w};
    float4 ha = {tH.x + sD.x - a * hd.x, tH.y + sD.y - a * hd.y,
                 tH.z + sD.z - a * hd.z, tH.w + sD.w - a * hd.w};
    float4 dg = {sH.x + tD.x - a * hd.x, sH.y + tD.y - a * hd.y,
                 sH.z + tD.z - a * hd.z, sH.w + tD.w - a * hd.w};
    *f4(hagg + (size_t)i * D + d4) = ha;
    *f4(dagg + (size_t)i * D + d4) = dg;
}

extern "C" void kernel_launch(void* const* d_in, const int* in_sizes, int n_in,
                              void* d_out, int out_size, void* d_ws, size_t ws_size,
                              hipStream_t stream) {
    const float* head = (const float*)d_in[0];
    const float* dep = (const float*)d_in[1];
    const float* tpA[2] = {(const float*)d_in[2], (const float*)d_in[5]};
    const float* tpb1[2] = {(const float*)d_in[3], (const float*)d_in[6]};
    const float* tpb2[2] = {(const float*)d_in[4], (const float*)d_in[7]};
    const float* awh[2] = {(const float*)d_in[8], (const float*)d_in[12]};
    const float* awd[2] = {(const float*)d_in[9], (const float*)d_in[13]};
    const float* cwh[2] = {(const float*)d_in[10], (const float*)d_in[14]};
    const float* cwd[2] = {(const float*)d_in[11], (const float*)d_in[15]};

    float* out = (float*)d_out;
    float* outHead = out;
    float* outDep = out + (size_t)N * D;
    float* alpha1 = out + (size_t)2 * N * D;
    float* alpha2 = alpha1 + (size_t)N * N;

    float* w = (float*)d_ws;
    float* S = w;               w += (size_t)N * 2 * D;   // Z overlays S (disjoint lifetimes)
    float* Z = S;
    float* T = w;               w += (size_t)N * 2 * D;
    float* bh = w;              w += N;
    float* bd = w;              w += N;
    float* da = w;              w += N;
    float* hagg = w;            w += (size_t)N * D;
    float* dagg = w;            w += (size_t)N * D;
    float* H1 = w;              w += (size_t)N * D;
    float* D1 = w;              w += (size_t)N * D;

    for (int L = 0; L < 2; L++) {
        const float* Hin = L ? H1 : head;
        const float* Din = L ? D1 : dep;
        float* Hout = L ? outHead : H1;
        float* Dout = L ? outDep : D1;
        float* alpha = L ? alpha2 : alpha1;

        rowdot_kernel<<<N / 4, 256, 0, stream>>>(Hin, tpb1[L], bh);
        rowdot_kernel<<<N / 4, 256, 0, stream>>>(Din, tpb2[L], bd);
        gemm_nk256_kernel<<<dim3(D / 64, N / 64), 256, 0, stream>>>(Hin, tpA[L], Z);
        logits_kernel<<<dim3(N / 128, N / 128), 256, 0, stream>>>(Z, Din, bh, bd, alpha);
        softmax_kernel<<<N, 256, 0, stream>>>(alpha);
        diag_kernel<<<N / 256, 256, 0, stream>>>(alpha, da);
        agg_kernel<<<dim3(2, N / 128, 2), 512, 0, stream>>>(alpha, Hin, Din, S, T);
        combine_kernel<<<(N * D / 4) / 256, 256, 0, stream>>>(S, T, da, Hin, Din, hagg, dagg);
        update_kernel<<<dim3(D / 64, N / 64), 256, 0, stream>>>(hagg, awh[L], Hin, cwh[L], Hout);
        update_kernel<<<dim3(D / 64, N / 64), 256, 0, stream>>>(dagg, awd[L], Din, cwd[L], Dout);
    }
}

// Round 2
// 3621.672 us; speedup vs baseline: 1.3319x; 1.3319x over previous
//
#include <hip/hip_runtime.h>

constexpr int N = 8192;
constexpr int D = 256;

typedef __attribute__((ext_vector_type(8))) short short8v;
typedef __attribute__((ext_vector_type(4))) short short4v;
typedef __attribute__((ext_vector_type(4))) float f32x4;

__device__ __forceinline__ const float4* f4c(const float* p) { return reinterpret_cast<const float4*>(p); }
__device__ __forceinline__ float4* f4(float* p) { return reinterpret_cast<float4*>(p); }

__device__ __forceinline__ short f2bf(float f) {
    unsigned u = __builtin_bit_cast(unsigned, f);
    u += 0x7fff + ((u >> 16) & 1);
    return (short)(u >> 16);
}
__device__ __forceinline__ float bf2f(short s) {
    unsigned u = ((unsigned)(unsigned short)s) << 16;
    return __builtin_bit_cast(float, u);
}

// exact 3-way bf16 split: x == bf2f(s0)+bf2f(s1)+bf2f(s2) (24 mantissa bits)
template <int NT>
__device__ __forceinline__ void split3(float x, short& s0, short& s1, short& s2) {
    s0 = f2bf(x);
    if constexpr (NT > 1) {
        float r = x - bf2f(s0);
        s1 = f2bf(r);
        float r2 = r - bf2f(s1);
        s2 = f2bf(r2);
    }
}

// ---------------------------------------------------------------------------
// agg via MFMA:  TRANS=0: out = alpha @ X ; TRANS=1: out = alpha^T @ X
// X = [H | Dp] logical N x 512. out is N x 512.
// NTERMS=6: fp32-grade via 3-way split (layer 1). NTERMS=1: plain bf16 (layer 2).
// Tile: BM=128 (rows, by), BN=128 (cols, bx in 0..3), BK=32, 256 threads,
// 4 waves in 2x2, each wave 64x64 via 4x4 frags of 16x16x32 MFMA.
// LDS tiles stored [row][kcol] with K-block XOR swizzle: for element (row,k):
//   col = (k&7) | (((k>>3) ^ ((row>>4)&3)) << 3)
// ---------------------------------------------------------------------------
template <int NTERMS, int TRANS>
__global__ __launch_bounds__(256, NTERMS == 1 ? 3 : 2)
void agg_mfma(const float* __restrict__ alpha, const float* __restrict__ H,
              const float* __restrict__ Dp, float* __restrict__ out) {
    constexpr int NS = (NTERMS == 1) ? 1 : 3;
    __shared__ short As[NS][128][40];
    __shared__ short Bs[NS][128][40];

    const int t = threadIdx.x;
    const int bx = blockIdx.x;           // n-tile over 512 cols
    const int i0 = blockIdx.y * 128;     // m-tile
    const float* Bsrc = (bx < 2) ? (H + bx * 128) : (Dp + (bx - 2) * 128);

    const int lane = t & 63;
    const int w = t >> 6;
    const int wm = w >> 1, wn = w & 1;
    const int fr = lane & 15, fq = lane >> 4;

    f32x4 acc[4][4];
#pragma unroll
    for (int a = 0; a < 4; a++)
#pragma unroll
        for (int b = 0; b < 4; b++) acc[a][b] = (f32x4){0.f, 0.f, 0.f, 0.f};

    // staging thread maps
    const int sm = t >> 1;                 // TRANS=0 A: row, 0..127
    const int skh = (t & 1) << 4;          // TRANS=0 A: k-half
    const int skk = t >> 3;                // scatter: k row, 0..31
    const int sc0 = (t & 7) << 4;          // scatter: col offset, 0..112

#pragma unroll 1
    for (int k0 = 0; k0 < N; k0 += 32) {
        // ---- stage A (alpha tile) ----
        if constexpr (TRANS == 0) {
            const float* src = alpha + (size_t)(i0 + sm) * N + k0 + skh;
            const int swz = (sm >> 4) & 3;
#pragma unroll
            for (int q = 0; q < 4; q++) {
                float4 v = f4c(src)[q];
                int k = skh + 4 * q;
                int col = ((((k >> 3) ^ swz)) << 3) | (k & 4);
                float vv[4] = {v.x, v.y, v.z, v.w};
                short a0[4], a1[4], a2[4];
#pragma unroll
                for (int e = 0; e < 4; e++) split3<NTERMS>(vv[e], a0[e], a1[e], a2[e]);
                *(short4v*)&As[0][sm][col] = (short4v){a0[0], a0[1], a0[2], a0[3]};
                if constexpr (NTERMS > 1) {
                    *(short4v*)&As[1][sm][col] = (short4v){a1[0], a1[1], a1[2], a1[3]};
                    *(short4v*)&As[2][sm][col] = (short4v){a2[0], a2[1], a2[2], a2[3]};
                }
            }
        } else {
            // A[m][k] = alpha[k0+k][i0+m] : read rows of alpha, scatter to LDS
            const float* src = alpha + (size_t)(k0 + skk) * N + i0 + sc0;
#pragma unroll
            for (int q = 0; q < 4; q++) {
                float4 v = f4c(src)[q];
                float vv[4] = {v.x, v.y, v.z, v.w};
#pragma unroll
                for (int e = 0; e < 4; e++) {
                    int m = sc0 + 4 * q + e;
                    int swz = (m >> 4) & 3;
                    int col = (skk & 7) | ((((skk >> 3) ^ swz)) << 3);
                    short a0, a1, a2;
                    split3<NTERMS>(vv[e], a0, a1, a2);
                    As[0][m][col] = a0;
                    if constexpr (NTERMS > 1) { As[1][m][col] = a1; As[2][m][col] = a2; }
                }
            }
        }
        // ---- stage B (X tile, transposed to [n][k]) ----
        {
            const float* src = Bsrc + (size_t)(k0 + skk) * D + sc0;
#pragma unroll
            for (int q = 0; q < 4; q++) {
                float4 v = f4c(src)[q];
                float vv[4] = {v.x, v.y, v.z, v.w};
#pragma unroll
                for (int e = 0; e < 4; e++) {
                    int n = sc0 + 4 * q + e;
                    int swz = (n >> 4) & 3;
                    int col = (skk & 7) | ((((skk >> 3) ^ swz)) << 3);
                    short b0, b1, b2;
                    split3<NTERMS>(vv[e], b0, b1, b2);
                    Bs[0][n][col] = b0;
                    if constexpr (NTERMS > 1) { Bs[1][n][col] = b1; Bs[2][n][col] = b2; }
                }
            }
        }
        __syncthreads();

        // ---- fragments + MFMA ----
        short8v af[NS][4], bg[NS][4];
#pragma unroll
        for (int mr = 0; mr < 4; mr++) {
            int row = wm * 64 + mr * 16 + fr;
            int cidx = 8 * (fq ^ ((wm * 4 + mr) & 3));
#pragma unroll
            for (int s = 0; s < NS; s++) af[s][mr] = *(const short8v*)&As[s][row][cidx];
        }
#pragma unroll
        for (int nr = 0; nr < 4; nr++) {
            int rowb = wn * 64 + nr * 16 + fr;
            int cidx = 8 * (fq ^ ((wn * 4 + nr) & 3));
#pragma unroll
            for (int s = 0; s < NS; s++) bg[s][nr] = *(const short8v*)&Bs[s][rowb][cidx];
        }
#pragma unroll
        for (int mr = 0; mr < 4; mr++) {
#pragma unroll
            for (int nr = 0; nr < 4; nr++) {
                f32x4 a = acc[mr][nr];
                a = __builtin_amdgcn_mfma_f32_16x16x32_bf16(af[0][mr], bg[0][nr], a, 0, 0, 0);
                if constexpr (NTERMS > 1) {
                    a = __builtin_amdgcn_mfma_f32_16x16x32_bf16(af[0][mr], bg[1][nr], a, 0, 0, 0);
                    a = __builtin_amdgcn_mfma_f32_16x16x32_bf16(af[1][mr], bg[0][nr], a, 0, 0, 0);
                    a = __builtin_amdgcn_mfma_f32_16x16x32_bf16(af[1][mr], bg[1][nr], a, 0, 0, 0);
                    a = __builtin_amdgcn_mfma_f32_16x16x32_bf16(af[0][mr], bg[2][nr], a, 0, 0, 0);
                    a = __builtin_amdgcn_mfma_f32_16x16x32_bf16(af[2][mr], bg[0][nr], a, 0, 0, 0);
                }
                acc[mr][nr] = a;
            }
        }
        __syncthreads();
    }

    // ---- epilogue: C/D layout col=lane&15, row=(lane>>4)*4+reg ----
#pragma unroll
    for (int mr = 0; mr < 4; mr++) {
#pragma unroll
        for (int nr = 0; nr < 4; nr++) {
            int col = bx * 128 + wn * 64 + nr * 16 + fr;
#pragma unroll
            for (int j = 0; j < 4; j++) {
                int row = i0 + wm * 64 + mr * 16 + fq * 4 + j;
                out[(size_t)row * 512 + col] = acc[mr][nr][j];
            }
        }
    }
}

// ---------------------------------------------------------------------------
// out[i] = dot(X[i,:], v)
__global__ __launch_bounds__(256) void rowdot_kernel(const float* __restrict__ X,
                                                     const float* __restrict__ v,
                                                     float* __restrict__ out) {
    int lane = threadIdx.x & 63;
    int row = blockIdx.x * 4 + (threadIdx.x >> 6);
    float4 a = f4c(X + (size_t)row * D)[lane];
    float4 b = f4c(v)[lane];
    float s = a.x * b.x + a.y * b.y + a.z * b.z + a.w * b.w;
#pragma unroll
    for (int off = 32; off > 0; off >>= 1) s += __shfl_down(s, off);
    if (lane == 0) out[row] = s;
}

// C[M x 256] = A[M x 256] @ W[256 x 256]
__global__ __launch_bounds__(256) void gemm_nk256_kernel(const float* __restrict__ A,
                                                         const float* __restrict__ W,
                                                         float* __restrict__ C) {
    __shared__ float As[16][68];
    __shared__ float Bs[16][68];
    int t = threadIdx.x;
    int tx = t & 15, ty = t >> 4;
    int j0 = blockIdx.x * 64;
    int i0 = blockIdx.y * 64;
    float acc[4][4] = {};
    for (int k0 = 0; k0 < 256; k0 += 16) {
        {
            int m = t >> 2, k4 = (t & 3) * 4;
            float4 a = *f4c(A + (size_t)(i0 + m) * D + k0 + k4);
            As[k4 + 0][m] = a.x; As[k4 + 1][m] = a.y; As[k4 + 2][m] = a.z; As[k4 + 3][m] = a.w;
            int kk = t >> 4, c = (t & 15) * 4;
            *f4(&Bs[kk][c]) = *f4c(W + (size_t)(k0 + kk) * D + j0 + c);
        }
        __syncthreads();
#pragma unroll
        for (int kk = 0; kk < 16; kk++) {
            float4 av = *f4c(&As[kk][ty * 4]);
            float4 bv = *f4c(&Bs[kk][tx * 4]);
            float a[4] = {av.x, av.y, av.z, av.w};
            float b[4] = {bv.x, bv.y, bv.z, bv.w};
#pragma unroll
            for (int r = 0; r < 4; r++)
#pragma unroll
                for (int c = 0; c < 4; c++) acc[r][c] = fmaf(a[r], b[c], acc[r][c]);
        }
        __syncthreads();
    }
#pragma unroll
    for (int r = 0; r < 4; r++) {
        float4 o = {acc[r][0], acc[r][1], acc[r][2], acc[r][3]};
        *f4(C + (size_t)(i0 + ty * 4 + r) * D + j0 + tx * 4) = o;
    }
}

// newX = leakyrelu(A1@W1 + A2@W2)
__global__ __launch_bounds__(256) void update_kernel(const float* __restrict__ A1,
                                                     const float* __restrict__ W1,
                                                     const float* __restrict__ A2,
                                                     const float* __restrict__ W2,
                                                     float* __restrict__ C) {
    __shared__ float As[16][68];
    __shared__ float Bs[16][68];
    int t = threadIdx.x;
    int tx = t & 15, ty = t >> 4;
    int j0 = blockIdx.x * 64;
    int i0 = blockIdx.y * 64;
    float acc[4][4] = {};
#pragma unroll 1
    for (int pass = 0; pass < 2; pass++) {
        const float* Ap = pass ? A2 : A1;
        const float* Wp = pass ? W2 : W1;
        for (int k0 = 0; k0 < 256; k0 += 16) {
            {
                int m = t >> 2, k4 = (t & 3) * 4;
                float4 a = *f4c(Ap + (size_t)(i0 + m) * D + k0 + k4);
                As[k4 + 0][m] = a.x; As[k4 + 1][m] = a.y; As[k4 + 2][m] = a.z; As[k4 + 3][m] = a.w;
                int kk = t >> 4, c = (t & 15) * 4;
                *f4(&Bs[kk][c]) = *f4c(Wp + (size_t)(k0 + kk) * D + j0 + c);
            }
            __syncthreads();
#pragma unroll
            for (int kk = 0; kk < 16; kk++) {
                float4 av = *f4c(&As[kk][ty * 4]);
                float4 bv = *f4c(&Bs[kk][tx * 4]);
                float a[4] = {av.x, av.y, av.z, av.w};
                float b[4] = {bv.x, bv.y, bv.z, bv.w};
#pragma unroll
                for (int r = 0; r < 4; r++)
#pragma unroll
                    for (int c = 0; c < 4; c++) acc[r][c] = fmaf(a[r], b[c], acc[r][c]);
            }
            __syncthreads();
        }
    }
#pragma unroll
    for (int r = 0; r < 4; r++) {
        float o[4];
#pragma unroll
        for (int c = 0; c < 4; c++) {
            float x = acc[r][c];
            o[c] = x >= 0.f ? x : 0.1f * x;
        }
        float4 ov = {o[0], o[1], o[2], o[3]};
        *f4(C + (size_t)(i0 + ty * 4 + r) * D + j0 + tx * 4) = ov;
    }
}

// alpha[i,j] = Z[i,:]·Dp[j,:] + bh[i] + bd[j]
__global__ __launch_bounds__(256) void logits_kernel(const float* __restrict__ Z,
                                                     const float* __restrict__ Dp,
                                                     const float* __restrict__ bh,
                                                     const float* __restrict__ bd,
                                                     float* __restrict__ alpha) {
    __shared__ float As[32][132];
    __shared__ float Bs[32][132];
    int t = threadIdx.x;
    int tx = t & 15, ty = t >> 4;
    int j0 = blockIdx.x * 128;
    int i0 = blockIdx.y * 128;
    float acc[8][8] = {};
    for (int k0 = 0; k0 < 256; k0 += 32) {
#pragma unroll
        for (int r = 0; r < 4; r++) {
            int fid = r * 256 + t;
            int m = fid >> 3, k4 = (fid & 7) * 4;
            float4 a = *f4c(Z + (size_t)(i0 + m) * D + k0 + k4);
            As[k4 + 0][m] = a.x; As[k4 + 1][m] = a.y; As[k4 + 2][m] = a.z; As[k4 + 3][m] = a.w;
            float4 b = *f4c(Dp + (size_t)(j0 + m) * D + k0 + k4);
            Bs[k4 + 0][m] = b.x; Bs[k4 + 1][m] = b.y; Bs[k4 + 2][m] = b.z; Bs[k4 + 3][m] = b.w;
        }
        __syncthreads();
#pragma unroll 4
        for (int kk = 0; kk < 32; kk++) {
            float4 a0 = *f4c(&As[kk][ty * 8]);
            float4 a1 = *f4c(&As[kk][ty * 8 + 4]);
            float4 b0 = *f4c(&Bs[kk][tx * 8]);
            float4 b1 = *f4c(&Bs[kk][tx * 8 + 4]);
            float a[8] = {a0.x, a0.y, a0.z, a0.w, a1.x, a1.y, a1.z, a1.w};
            float b[8] = {b0.x, b0.y, b0.z, b0.w, b1.x, b1.y, b1.z, b1.w};
#pragma unroll
            for (int r = 0; r < 8; r++)
#pragma unroll
                for (int c = 0; c < 8; c++) acc[r][c] = fmaf(a[r], b[c], acc[r][c]);
        }
        __syncthreads();
    }
    float4 bd0 = *f4c(bd + j0 + tx * 8);
    float4 bd1 = *f4c(bd + j0 + tx * 8 + 4);
#pragma unroll
    for (int r = 0; r < 8; r++) {
        float bhr = bh[i0 + ty * 8 + r];
        float4 o0 = {acc[r][0] + bhr + bd0.x, acc[r][1] + bhr + bd0.y,
                     acc[r][2] + bhr + bd0.z, acc[r][3] + bhr + bd0.w};
        float4 o1 = {acc[r][4] + bhr + bd1.x, acc[r][5] + bhr + bd1.y,
                     acc[r][6] + bhr + bd1.z, acc[r][7] + bhr + bd1.w};
        float* orow = alpha + (size_t)(i0 + ty * 8 + r) * N + j0 + tx * 8;
        f4(orow)[0] = o0;
        f4(orow)[1] = o1;
    }
}

__global__ __launch_bounds__(256) void softmax_kernel(float* __restrict__ alpha) {
    int row = blockIdx.x;
    int t = threadIdx.x;
    float4* rp = f4(alpha + (size_t)row * N);
    float4 v[8];
    float m = -3.4e38f;
#pragma unroll
    for (int i = 0; i < 8; i++) {
        v[i] = rp[i * 256 + t];
        m = fmaxf(m, fmaxf(fmaxf(v[i].x, v[i].y), fmaxf(v[i].z, v[i].w)));
    }
    __shared__ float red[8];
#pragma unroll
    for (int off = 32; off > 0; off >>= 1) m = fmaxf(m, __shfl_xor(m, off));
    if ((t & 63) == 0) red[t >> 6] = m;
    __syncthreads();
    m = fmaxf(fmaxf(red[0], red[1]), fmaxf(red[2], red[3]));
    float s = 0.f;
#pragma unroll
    for (int i = 0; i < 8; i++) {
        v[i].x = __expf(v[i].x - m);
        v[i].y = __expf(v[i].y - m);
        v[i].z = __expf(v[i].z - m);
        v[i].w = __expf(v[i].w - m);
        s += v[i].x + v[i].y + v[i].z + v[i].w;
    }
#pragma unroll
    for (int off = 32; off > 0; off >>= 1) s += __shfl_xor(s, off);
    if ((t & 63) == 0) red[4 + (t >> 6)] = s;
    __syncthreads();
    s = red[4] + red[5] + red[6] + red[7];
    float inv = 1.f / s;
#pragma unroll
    for (int i = 0; i < 8; i++) {
        v[i].x *= inv; v[i].y *= inv; v[i].z *= inv; v[i].w *= inv;
        rp[i * 256 + t] = v[i];
    }
}

__global__ __launch_bounds__(256) void diag_kernel(const float* __restrict__ alpha,
                                                   float* __restrict__ da) {
    int i = blockIdx.x * 256 + threadIdx.x;
    da[i] = alpha[(size_t)i * N + i];
}

__global__ __launch_bounds__(256) void combine_kernel(const float* __restrict__ S,
                                                      const float* __restrict__ T,
                                                      const float* __restrict__ da,
                                                      const float* __restrict__ H,
                                                      const float* __restrict__ Dp,
                                                      float* __restrict__ hagg,
                                                      float* __restrict__ dagg) {
    int gid = blockIdx.x * 256 + threadIdx.x;
    int i = gid >> 6;
    int d4 = (gid & 63) * 4;
    float a = da[i];
    float4 sH = *f4c(S + (size_t)i * (2 * D) + d4);
    float4 sD = *f4c(S + (size_t)i * (2 * D) + D + d4);
    float4 tH = *f4c(T + (size_t)i * (2 * D) + d4);
    float4 tD = *f4c(T + (size_t)i * (2 * D) + D + d4);
    float4 h = *f4c(H + (size_t)i * D + d4);
    float4 dp = *f4c(Dp + (size_t)i * D + d4);
    float4 hd = {h.x + dp.x, h.y + dp.y, h.z + dp.z, h.w + dp.w};
    float4 ha = {tH.x + sD.x - a * hd.x, tH.y + sD.y - a * hd.y,
                 tH.z + sD.z - a * hd.z, tH.w + sD.w - a * hd.w};
    float4 dg = {sH.x + tD.x - a * hd.x, sH.y + tD.y - a * hd.y,
                 sH.z + tD.z - a * hd.z, sH.w + tD.w - a * hd.w};
    *f4(hagg + (size_t)i * D + d4) = ha;
    *f4(dagg + (size_t)i * D + d4) = dg;
}

extern "C" void kernel_launch(void* const* d_in, const int* in_sizes, int n_in,
                              void* d_out, int out_size, void* d_ws, size_t ws_size,
                              hipStream_t stream) {
    const float* head = (const float*)d_in[0];
    const float* dep = (const float*)d_in[1];
    const float* tpA[2] = {(const float*)d_in[2], (const float*)d_in[5]};
    const float* tpb1[2] = {(const float*)d_in[3], (const float*)d_in[6]};
    const float* tpb2[2] = {(const float*)d_in[4], (const float*)d_in[7]};
    const float* awh[2] = {(const float*)d_in[8], (const float*)d_in[12]};
    const float* awd[2] = {(const float*)d_in[9], (const float*)d_in[13]};
    const float* cwh[2] = {(const float*)d_in[10], (const float*)d_in[14]};
    const float* cwd[2] = {(const float*)d_in[11], (const float*)d_in[15]};

    float* out = (float*)d_out;
    float* outHead = out;
    float* outDep = out + (size_t)N * D;
    float* alpha1 = out + (size_t)2 * N * D;
    float* alpha2 = alpha1 + (size_t)N * N;

    float* w = (float*)d_ws;
    float* S = w;               w += (size_t)N * 2 * D;   // Z overlays S (disjoint lifetimes)
    float* Z = S;
    float* T = w;               w += (size_t)N * 2 * D;
    float* bh = w;              w += N;
    float* bd = w;              w += N;
    float* da = w;              w += N;
    float* hagg = w;            w += (size_t)N * D;
    float* dagg = w;            w += (size_t)N * D;
    float* H1 = w;              w += (size_t)N * D;
    float* D1 = w;              w += (size_t)N * D;

    for (int L = 0; L < 2; L++) {
        const float* Hin = L ? H1 : head;
        const float* Din = L ? D1 : dep;
        float* Hout = L ? outHead : H1;
        float* Dout = L ? outDep : D1;
        float* alpha = L ? alpha2 : alpha1;

        rowdot_kernel<<<N / 4, 256, 0, stream>>>(Hin, tpb1[L], bh);
        rowdot_kernel<<<N / 4, 256, 0, stream>>>(Din, tpb2[L], bd);
        gemm_nk256_kernel<<<dim3(D / 64, N / 64), 256, 0, stream>>>(Hin, tpA[L], Z);
        logits_kernel<<<dim3(N / 128, N / 128), 256, 0, stream>>>(Z, Din, bh, bd, alpha);
        softmax_kernel<<<N, 256, 0, stream>>>(alpha);
        diag_kernel<<<N / 256, 256, 0, stream>>>(alpha, da);
        if (L == 0) {
            agg_mfma<6, 0><<<dim3(4, N / 128), 256, 0, stream>>>(alpha, Hin, Din, S);
            agg_mfma<6, 1><<<dim3(4, N / 128), 256, 0, stream>>>(alpha, Hin, Din, T);
        } else {
            agg_mfma<1, 0><<<dim3(4, N / 128), 256, 0, stream>>>(alpha, Hin, Din, S);
            agg_mfma<1, 1><<<dim3(4, N / 128), 256, 0, stream>>>(alpha, Hin, Din, T);
        }
        combine_kernel<<<(N * D / 4) / 256, 256, 0, stream>>>(S, T, da, Hin, Din, hagg, dagg);
        update_kernel<<<dim3(D / 64, N / 64), 256, 0, stream>>>(hagg, awh[L], Hin, cwh[L], Hout);
        update_kernel<<<dim3(D / 64, N / 64), 256, 0, stream>>>(dagg, awd[L], Din, cwd[L], Dout);
    }
}

// Round 3
// 2411.966 us; speedup vs baseline: 1.9999x; 1.5015x over previous
//
#include <hip/hip_runtime.h>

constexpr int N = 8192;
constexpr int D = 256;

typedef __attribute__((ext_vector_type(8))) short short8v;
typedef __attribute__((ext_vector_type(4))) short short4v;
typedef __attribute__((ext_vector_type(4))) float f32x4;

__device__ __forceinline__ const float4* f4c(const float* p) { return reinterpret_cast<const float4*>(p); }
__device__ __forceinline__ float4* f4(float* p) { return reinterpret_cast<float4*>(p); }

__device__ __forceinline__ short f2bf(float f) {
    unsigned u = __builtin_bit_cast(unsigned, f);
    u += 0x7fff + ((u >> 16) & 1);
    return (short)(u >> 16);
}
__device__ __forceinline__ float bf2f(short s) {
    unsigned u = ((unsigned)(unsigned short)s) << 16;
    return __builtin_bit_cast(float, u);
}

// split into up-to-3 bf16 limbs; identical math to round-2 split3
template <int NS>
__device__ __forceinline__ void splitN(float x, short* s) {
    s[0] = f2bf(x);
    if constexpr (NS > 1) {
        float r = x - bf2f(s[0]);
        s[1] = f2bf(r);
        s[2] = f2bf(r - bf2f(s[1]));
    }
}

// ===========================================================================
// NEW plane-based agg:  z=0: S = alpha @ X ; z=1: T = alpha^T @ X
// aP: [NS][N][N] bf16 planes of alpha (row-major)
// xP: [NS][512][N] bf16 planes of X^T (X = [H | Dp], stored column-major)
// Block 128x128, 4 waves 2x2, wave 64x64 via 4x4 frags of 16x16x32 MFMA.
// LDS [row][40] with 16B-granule XOR swizzle: colgranule = (k>>3) ^ ((row>>4)&3)
// ===========================================================================
template <int NS>
__global__ __launch_bounds__(256, 2)
void agg_planes(const unsigned short* __restrict__ aP,
                const unsigned short* __restrict__ xP,
                float* __restrict__ S, float* __restrict__ T) {
    __shared__ unsigned short As[NS][128][40];
    __shared__ unsigned short Bs[NS][128][40];
    const int t = threadIdx.x;
    const int bx = blockIdx.x;          // 0..3 over 512 output cols
    const int i0 = blockIdx.y * 128;
    const int trans = blockIdx.z;
    float* __restrict__ out = trans ? T : S;
    const size_t aStride = (size_t)N * N;
    const size_t xStride = (size_t)512 * N;

    const int lane = t & 63, w = t >> 6, wm = w >> 1, wn = w & 1;
    const int fr = lane & 15, fq = lane >> 4;

    f32x4 acc[4][4];
#pragma unroll
    for (int a = 0; a < 4; a++)
#pragma unroll
        for (int b = 0; b < 4; b++) acc[a][b] = (f32x4){0.f, 0.f, 0.f, 0.f};

#pragma unroll 1
    for (int k0 = 0; k0 < N; k0 += 32) {
        // ---- stage B (X^T planes, row-contiguous) ----
#pragma unroll
        for (int s = 0; s < NS; s++) {
#pragma unroll
            for (int g = 0; g < 2; g++) {
                int gid = g * 256 + t;
                int n = gid >> 2, gk = gid & 3;
                short8v v = *(const short8v*)(xP + s * xStride +
                                              (size_t)(bx * 128 + n) * N + k0 + gk * 8);
                *(short8v*)&Bs[s][n][(gk ^ ((n >> 4) & 3)) << 3] = v;
            }
        }
        // ---- stage A (alpha planes) ----
        if (!trans) {
#pragma unroll
            for (int s = 0; s < NS; s++) {
#pragma unroll
                for (int g = 0; g < 2; g++) {
                    int gid = g * 256 + t;
                    int m = gid >> 2, gk = gid & 3;
                    short8v v = *(const short8v*)(aP + s * aStride +
                                                  (size_t)(i0 + m) * N + k0 + gk * 8);
                    *(short8v*)&As[s][m][(gk ^ ((m >> 4) & 3)) << 3] = v;
                }
            }
        } else {
#pragma unroll
            for (int s = 0; s < NS; s++) {
#pragma unroll
                for (int g = 0; g < 2; g++) {
                    int gid = g * 256 + t;
                    int kk = gid >> 4, gm = gid & 15;
                    short8v v = *(const short8v*)(aP + s * aStride +
                                                  (size_t)(k0 + kk) * N + i0 + gm * 8);
#pragma unroll
                    for (int e = 0; e < 8; e++) {
                        int m = gm * 8 + e;
                        int col = (kk & 7) | ((((kk >> 3) ^ ((m >> 4) & 3))) << 3);
                        As[s][m][col] = (unsigned short)v[e];
                    }
                }
            }
        }
        __syncthreads();

        short8v af[NS][4], bg[NS][4];
#pragma unroll
        for (int mr = 0; mr < 4; mr++) {
            int row = wm * 64 + mr * 16 + fr;
            int cidx = 8 * (fq ^ ((wm * 4 + mr) & 3));
#pragma unroll
            for (int s = 0; s < NS; s++) af[s][mr] = *(const short8v*)&As[s][row][cidx];
        }
#pragma unroll
        for (int nr = 0; nr < 4; nr++) {
            int rowb = wn * 64 + nr * 16 + fr;
            int cidx = 8 * (fq ^ ((wn * 4 + nr) & 3));
#pragma unroll
            for (int s = 0; s < NS; s++) bg[s][nr] = *(const short8v*)&Bs[s][rowb][cidx];
        }
#pragma unroll
        for (int mr = 0; mr < 4; mr++) {
#pragma unroll
            for (int nr = 0; nr < 4; nr++) {
                f32x4 a = acc[mr][nr];
                a = __builtin_amdgcn_mfma_f32_16x16x32_bf16(af[0][mr], bg[0][nr], a, 0, 0, 0);
                if constexpr (NS > 1) {
                    a = __builtin_amdgcn_mfma_f32_16x16x32_bf16(af[0][mr], bg[1][nr], a, 0, 0, 0);
                    a = __builtin_amdgcn_mfma_f32_16x16x32_bf16(af[1][mr], bg[0][nr], a, 0, 0, 0);
                    a = __builtin_amdgcn_mfma_f32_16x16x32_bf16(af[1][mr], bg[1][nr], a, 0, 0, 0);
                    a = __builtin_amdgcn_mfma_f32_16x16x32_bf16(af[0][mr], bg[2][nr], a, 0, 0, 0);
                    a = __builtin_amdgcn_mfma_f32_16x16x32_bf16(af[2][mr], bg[0][nr], a, 0, 0, 0);
                }
                acc[mr][nr] = a;
            }
        }
        __syncthreads();
    }

#pragma unroll
    for (int mr = 0; mr < 4; mr++) {
#pragma unroll
        for (int nr = 0; nr < 4; nr++) {
            int col = bx * 128 + wn * 64 + nr * 16 + fr;
#pragma unroll
            for (int j = 0; j < 4; j++) {
                int row = i0 + wm * 64 + mr * 16 + fq * 4 + j;
                out[(size_t)row * 512 + col] = acc[mr][nr][j];
            }
        }
    }
}

// X^T split planes: xP[s][n][k], n in [0,512) = cols of [H|Dp], k = node.
template <int NS>
__global__ __launch_bounds__(256) void splitX_kernel(const float* __restrict__ H,
                                                     const float* __restrict__ Dp,
                                                     unsigned short* __restrict__ xP) {
    __shared__ float tile[64][68];
    const int t = threadIdx.x;
    const int k0 = blockIdx.x * 64;
    const int n0 = blockIdx.y * 64;
    const float* src = (n0 < 256) ? H : Dp;
    const int c0 = n0 & 255;
    const size_t xStride = (size_t)512 * N;
#pragma unroll
    for (int q = 0; q < 4; q++) {
        int k = q * 16 + (t >> 4);
        int n4 = (t & 15) * 4;
        float4 v = *f4c(src + (size_t)(k0 + k) * D + c0 + n4);
        tile[k][n4] = v.x; tile[k][n4 + 1] = v.y; tile[k][n4 + 2] = v.z; tile[k][n4 + 3] = v.w;
    }
    __syncthreads();
#pragma unroll
    for (int q = 0; q < 4; q++) {
        int n = q * 16 + (t >> 4);
        int k4 = (t & 15) * 4;
        short sp[3][4];
#pragma unroll
        for (int e = 0; e < 4; e++) {
            short tmp[3];
            splitN<NS>(tile[k4 + e][n], tmp);
            sp[0][e] = tmp[0];
            if constexpr (NS > 1) { sp[1][e] = tmp[1]; sp[2][e] = tmp[2]; }
        }
#pragma unroll
        for (int s = 0; s < NS; s++)
            *(short4v*)(xP + s * xStride + (size_t)(n0 + n) * N + k0 + k4) =
                (short4v){sp[s][0], sp[s][1], sp[s][2], sp[s][3]};
    }
}

// softmax fused with alpha bf16 plane emission
template <int NS>
__global__ __launch_bounds__(256) void softmax_planes(float* __restrict__ alpha,
                                                      unsigned short* __restrict__ aP) {
    const int row = blockIdx.x;
    const int t = threadIdx.x;
    const size_t aStride = (size_t)N * N;
    float4* rp = f4(alpha + (size_t)row * N);
    float4 v[8];
    float m = -3.4e38f;
#pragma unroll
    for (int i = 0; i < 8; i++) {
        v[i] = rp[i * 256 + t];
        m = fmaxf(m, fmaxf(fmaxf(v[i].x, v[i].y), fmaxf(v[i].z, v[i].w)));
    }
    __shared__ float red[8];
#pragma unroll
    for (int off = 32; off > 0; off >>= 1) m = fmaxf(m, __shfl_xor(m, off));
    if ((t & 63) == 0) red[t >> 6] = m;
    __syncthreads();
    m = fmaxf(fmaxf(red[0], red[1]), fmaxf(red[2], red[3]));
    float s = 0.f;
#pragma unroll
    for (int i = 0; i < 8; i++) {
        v[i].x = __expf(v[i].x - m);
        v[i].y = __expf(v[i].y - m);
        v[i].z = __expf(v[i].z - m);
        v[i].w = __expf(v[i].w - m);
        s += v[i].x + v[i].y + v[i].z + v[i].w;
    }
#pragma unroll
    for (int off = 32; off > 0; off >>= 1) s += __shfl_xor(s, off);
    if ((t & 63) == 0) red[4 + (t >> 6)] = s;
    __syncthreads();
    s = red[4] + red[5] + red[6] + red[7];
    float inv = 1.f / s;
#pragma unroll
    for (int i = 0; i < 8; i++) {
        v[i].x *= inv; v[i].y *= inv; v[i].z *= inv; v[i].w *= inv;
        rp[i * 256 + t] = v[i];
        float vals[4] = {v[i].x, v[i].y, v[i].z, v[i].w};
        short sp[3][4];
#pragma unroll
        for (int e = 0; e < 4; e++) {
            short tmp[3];
            splitN<NS>(vals[e], tmp);
            sp[0][e] = tmp[0];
            if constexpr (NS > 1) { sp[1][e] = tmp[1]; sp[2][e] = tmp[2]; }
        }
        size_t base = (size_t)row * N + i * 1024 + t * 4;
#pragma unroll
        for (int ss = 0; ss < NS; ss++)
            *(short4v*)(aP + ss * aStride + base) =
                (short4v){sp[ss][0], sp[ss][1], sp[ss][2], sp[ss][3]};
    }
}

// ===========================================================================
// FALLBACK (round-2 proven): in-kernel split agg
// ===========================================================================
template <int NTERMS, int TRANS>
__global__ __launch_bounds__(256, NTERMS == 1 ? 3 : 2)
void agg_mfma(const float* __restrict__ alpha, const float* __restrict__ H,
              const float* __restrict__ Dp, float* __restrict__ out) {
    constexpr int NS = (NTERMS == 1) ? 1 : 3;
    __shared__ short As[NS][128][40];
    __shared__ short Bs[NS][128][40];
    const int t = threadIdx.x;
    const int bx = blockIdx.x;
    const int i0 = blockIdx.y * 128;
    const float* Bsrc = (bx < 2) ? (H + bx * 128) : (Dp + (bx - 2) * 128);
    const int lane = t & 63;
    const int w = t >> 6;
    const int wm = w >> 1, wn = w & 1;
    const int fr = lane & 15, fq = lane >> 4;
    f32x4 acc[4][4];
#pragma unroll
    for (int a = 0; a < 4; a++)
#pragma unroll
        for (int b = 0; b < 4; b++) acc[a][b] = (f32x4){0.f, 0.f, 0.f, 0.f};
    const int sm = t >> 1;
    const int skh = (t & 1) << 4;
    const int skk = t >> 3;
    const int sc0 = (t & 7) << 4;
#pragma unroll 1
    for (int k0 = 0; k0 < N; k0 += 32) {
        if constexpr (TRANS == 0) {
            const float* src = alpha + (size_t)(i0 + sm) * N + k0 + skh;
            const int swz = (sm >> 4) & 3;
#pragma unroll
            for (int q = 0; q < 4; q++) {
                float4 v = f4c(src)[q];
                int k = skh + 4 * q;
                int col = ((((k >> 3) ^ swz)) << 3) | (k & 4);
                float vv[4] = {v.x, v.y, v.z, v.w};
                short a0[4], a1[4], a2[4];
#pragma unroll
                for (int e = 0; e < 4; e++) {
                    short tmp[3];
                    splitN<NS>(vv[e], tmp);
                    a0[e] = tmp[0]; a1[e] = tmp[1]; a2[e] = tmp[2];
                }
                *(short4v*)&As[0][sm][col] = (short4v){a0[0], a0[1], a0[2], a0[3]};
                if constexpr (NTERMS > 1) {
                    *(short4v*)&As[1][sm][col] = (short4v){a1[0], a1[1], a1[2], a1[3]};
                    *(short4v*)&As[2][sm][col] = (short4v){a2[0], a2[1], a2[2], a2[3]};
                }
            }
        } else {
            const float* src = alpha + (size_t)(k0 + skk) * N + i0 + sc0;
#pragma unroll
            for (int q = 0; q < 4; q++) {
                float4 v = f4c(src)[q];
                float vv[4] = {v.x, v.y, v.z, v.w};
#pragma unroll
                for (int e = 0; e < 4; e++) {
                    int m = sc0 + 4 * q + e;
                    int swz = (m >> 4) & 3;
                    int col = (skk & 7) | ((((skk >> 3) ^ swz)) << 3);
                    short tmp[3];
                    splitN<NS>(vv[e], tmp);
                    As[0][m][col] = tmp[0];
                    if constexpr (NTERMS > 1) { As[1][m][col] = tmp[1]; As[2][m][col] = tmp[2]; }
                }
            }
        }
        {
            const float* src = Bsrc + (size_t)(k0 + skk) * D + sc0;
#pragma unroll
            for (int q = 0; q < 4; q++) {
                float4 v = f4c(src)[q];
                float vv[4] = {v.x, v.y, v.z, v.w};
#pragma unroll
                for (int e = 0; e < 4; e++) {
                    int n = sc0 + 4 * q + e;
                    int swz = (n >> 4) & 3;
                    int col = (skk & 7) | ((((skk >> 3) ^ swz)) << 3);
                    short tmp[3];
                    splitN<NS>(vv[e], tmp);
                    Bs[0][n][col] = tmp[0];
                    if constexpr (NTERMS > 1) { Bs[1][n][col] = tmp[1]; Bs[2][n][col] = tmp[2]; }
                }
            }
        }
        __syncthreads();
        short8v af[NS][4], bg[NS][4];
#pragma unroll
        for (int mr = 0; mr < 4; mr++) {
            int row = wm * 64 + mr * 16 + fr;
            int cidx = 8 * (fq ^ ((wm * 4 + mr) & 3));
#pragma unroll
            for (int s = 0; s < NS; s++) af[s][mr] = *(const short8v*)&As[s][row][cidx];
        }
#pragma unroll
        for (int nr = 0; nr < 4; nr++) {
            int rowb = wn * 64 + nr * 16 + fr;
            int cidx = 8 * (fq ^ ((wn * 4 + nr) & 3));
#pragma unroll
            for (int s = 0; s < NS; s++) bg[s][nr] = *(const short8v*)&Bs[s][rowb][cidx];
        }
#pragma unroll
        for (int mr = 0; mr < 4; mr++) {
#pragma unroll
            for (int nr = 0; nr < 4; nr++) {
                f32x4 a = acc[mr][nr];
                a = __builtin_amdgcn_mfma_f32_16x16x32_bf16(af[0][mr], bg[0][nr], a, 0, 0, 0);
                if constexpr (NTERMS > 1) {
                    a = __builtin_amdgcn_mfma_f32_16x16x32_bf16(af[0][mr], bg[1][nr], a, 0, 0, 0);
                    a = __builtin_amdgcn_mfma_f32_16x16x32_bf16(af[1][mr], bg[0][nr], a, 0, 0, 0);
                    a = __builtin_amdgcn_mfma_f32_16x16x32_bf16(af[1][mr], bg[1][nr], a, 0, 0, 0);
                    a = __builtin_amdgcn_mfma_f32_16x16x32_bf16(af[0][mr], bg[2][nr], a, 0, 0, 0);
                    a = __builtin_amdgcn_mfma_f32_16x16x32_bf16(af[2][mr], bg[0][nr], a, 0, 0, 0);
                }
                acc[mr][nr] = a;
            }
        }
        __syncthreads();
    }
#pragma unroll
    for (int mr = 0; mr < 4; mr++) {
#pragma unroll
        for (int nr = 0; nr < 4; nr++) {
            int col = bx * 128 + wn * 64 + nr * 16 + fr;
#pragma unroll
            for (int j = 0; j < 4; j++) {
                int row = i0 + wm * 64 + mr * 16 + fq * 4 + j;
                out[(size_t)row * 512 + col] = acc[mr][nr][j];
            }
        }
    }
}

// ---------------------------------------------------------------------------
__global__ __launch_bounds__(256) void rowdot_kernel(const float* __restrict__ X,
                                                     const float* __restrict__ v,
                                                     float* __restrict__ out) {
    int lane = threadIdx.x & 63;
    int row = blockIdx.x * 4 + (threadIdx.x >> 6);
    float4 a = f4c(X + (size_t)row * D)[lane];
    float4 b = f4c(v)[lane];
    float s = a.x * b.x + a.y * b.y + a.z * b.z + a.w * b.w;
#pragma unroll
    for (int off = 32; off > 0; off >>= 1) s += __shfl_down(s, off);
    if (lane == 0) out[row] = s;
}

__global__ __launch_bounds__(256) void gemm_nk256_kernel(const float* __restrict__ A,
                                                         const float* __restrict__ W,
                                                         float* __restrict__ C) {
    __shared__ float As[16][68];
    __shared__ float Bs[16][68];
    int t = threadIdx.x;
    int tx = t & 15, ty = t >> 4;
    int j0 = blockIdx.x * 64;
    int i0 = blockIdx.y * 64;
    float acc[4][4] = {};
    for (int k0 = 0; k0 < 256; k0 += 16) {
        {
            int m = t >> 2, k4 = (t & 3) * 4;
            float4 a = *f4c(A + (size_t)(i0 + m) * D + k0 + k4);
            As[k4 + 0][m] = a.x; As[k4 + 1][m] = a.y; As[k4 + 2][m] = a.z; As[k4 + 3][m] = a.w;
            int kk = t >> 4, c = (t & 15) * 4;
            *f4(&Bs[kk][c]) = *f4c(W + (size_t)(k0 + kk) * D + j0 + c);
        }
        __syncthreads();
#pragma unroll
        for (int kk = 0; kk < 16; kk++) {
            float4 av = *f4c(&As[kk][ty * 4]);
            float4 bv = *f4c(&Bs[kk][tx * 4]);
            float a[4] = {av.x, av.y, av.z, av.w};
            float b[4] = {bv.x, bv.y, bv.z, bv.w};
#pragma unroll
            for (int r = 0; r < 4; r++)
#pragma unroll
                for (int c = 0; c < 4; c++) acc[r][c] = fmaf(a[r], b[c], acc[r][c]);
        }
        __syncthreads();
    }
#pragma unroll
    for (int r = 0; r < 4; r++) {
        float4 o = {acc[r][0], acc[r][1], acc[r][2], acc[r][3]};
        *f4(C + (size_t)(i0 + ty * 4 + r) * D + j0 + tx * 4) = o;
    }
}

__global__ __launch_bounds__(256) void update_kernel(const float* __restrict__ A1,
                                                     const float* __restrict__ W1,
                                                     const float* __restrict__ A2,
                                                     const float* __restrict__ W2,
                                                     float* __restrict__ C) {
    __shared__ float As[16][68];
    __shared__ float Bs[16][68];
    int t = threadIdx.x;
    int tx = t & 15, ty = t >> 4;
    int j0 = blockIdx.x * 64;
    int i0 = blockIdx.y * 64;
    float acc[4][4] = {};
#pragma unroll 1
    for (int pass = 0; pass < 2; pass++) {
        const float* Ap = pass ? A2 : A1;
        const float* Wp = pass ? W2 : W1;
        for (int k0 = 0; k0 < 256; k0 += 16) {
            {
                int m = t >> 2, k4 = (t & 3) * 4;
                float4 a = *f4c(Ap + (size_t)(i0 + m) * D + k0 + k4);
                As[k4 + 0][m] = a.x; As[k4 + 1][m] = a.y; As[k4 + 2][m] = a.z; As[k4 + 3][m] = a.w;
                int kk = t >> 4, c = (t & 15) * 4;
                *f4(&Bs[kk][c]) = *f4c(Wp + (size_t)(k0 + kk) * D + j0 + c);
            }
            __syncthreads();
#pragma unroll
            for (int kk = 0; kk < 16; kk++) {
                float4 av = *f4c(&As[kk][ty * 4]);
                float4 bv = *f4c(&Bs[kk][tx * 4]);
                float a[4] = {av.x, av.y, av.z, av.w};
                float b[4] = {bv.x, bv.y, bv.z, bv.w};
#pragma unroll
                for (int r = 0; r < 4; r++)
#pragma unroll
                    for (int c = 0; c < 4; c++) acc[r][c] = fmaf(a[r], b[c], acc[r][c]);
            }
            __syncthreads();
        }
    }
#pragma unroll
    for (int r = 0; r < 4; r++) {
        float o[4];
#pragma unroll
        for (int c = 0; c < 4; c++) {
            float x = acc[r][c];
            o[c] = x >= 0.f ? x : 0.1f * x;
        }
        float4 ov = {o[0], o[1], o[2], o[3]};
        *f4(C + (size_t)(i0 + ty * 4 + r) * D + j0 + tx * 4) = ov;
    }
}

__global__ __launch_bounds__(256) void logits_kernel(const float* __restrict__ Z,
                                                     const float* __restrict__ Dp,
                                                     const float* __restrict__ bh,
                                                     const float* __restrict__ bd,
                                                     float* __restrict__ alpha) {
    __shared__ float As[32][132];
    __shared__ float Bs[32][132];
    int t = threadIdx.x;
    int tx = t & 15, ty = t >> 4;
    int j0 = blockIdx.x * 128;
    int i0 = blockIdx.y * 128;
    float acc[8][8] = {};
    for (int k0 = 0; k0 < 256; k0 += 32) {
#pragma unroll
        for (int r = 0; r < 4; r++) {
            int fid = r * 256 + t;
            int m = fid >> 3, k4 = (fid & 7) * 4;
            float4 a = *f4c(Z + (size_t)(i0 + m) * D + k0 + k4);
            As[k4 + 0][m] = a.x; As[k4 + 1][m] = a.y; As[k4 + 2][m] = a.z; As[k4 + 3][m] = a.w;
            float4 b = *f4c(Dp + (size_t)(j0 + m) * D + k0 + k4);
            Bs[k4 + 0][m] = b.x; Bs[k4 + 1][m] = b.y; Bs[k4 + 2][m] = b.z; Bs[k4 + 3][m] = b.w;
        }
        __syncthreads();
#pragma unroll 4
        for (int kk = 0; kk < 32; kk++) {
            float4 a0 = *f4c(&As[kk][ty * 8]);
            float4 a1 = *f4c(&As[kk][ty * 8 + 4]);
            float4 b0 = *f4c(&Bs[kk][tx * 8]);
            float4 b1 = *f4c(&Bs[kk][tx * 8 + 4]);
            float a[8] = {a0.x, a0.y, a0.z, a0.w, a1.x, a1.y, a1.z, a1.w};
            float b[8] = {b0.x, b0.y, b0.z, b0.w, b1.x, b1.y, b1.z, b1.w};
#pragma unroll
            for (int r = 0; r < 8; r++)
#pragma unroll
                for (int c = 0; c < 8; c++) acc[r][c] = fmaf(a[r], b[c], acc[r][c]);
        }
        __syncthreads();
    }
    float4 bd0 = *f4c(bd + j0 + tx * 8);
    float4 bd1 = *f4c(bd + j0 + tx * 8 + 4);
#pragma unroll
    for (int r = 0; r < 8; r++) {
        float bhr = bh[i0 + ty * 8 + r];
        float4 o0 = {acc[r][0] + bhr + bd0.x, acc[r][1] + bhr + bd0.y,
                     acc[r][2] + bhr + bd0.z, acc[r][3] + bhr + bd0.w};
        float4 o1 = {acc[r][4] + bhr + bd1.x, acc[r][5] + bhr + bd1.y,
                     acc[r][6] + bhr + bd1.z, acc[r][7] + bhr + bd1.w};
        float* orow = alpha + (size_t)(i0 + ty * 8 + r) * N + j0 + tx * 8;
        f4(orow)[0] = o0;
        f4(orow)[1] = o1;
    }
}

// fallback softmax (no planes)
__global__ __launch_bounds__(256) void softmax_kernel(float* __restrict__ alpha) {
    int row = blockIdx.x;
    int t = threadIdx.x;
    float4* rp = f4(alpha + (size_t)row * N);
    float4 v[8];
    float m = -3.4e38f;
#pragma unroll
    for (int i = 0; i < 8; i++) {
        v[i] = rp[i * 256 + t];
        m = fmaxf(m, fmaxf(fmaxf(v[i].x, v[i].y), fmaxf(v[i].z, v[i].w)));
    }
    __shared__ float red[8];
#pragma unroll
    for (int off = 32; off > 0; off >>= 1) m = fmaxf(m, __shfl_xor(m, off));
    if ((t & 63) == 0) red[t >> 6] = m;
    __syncthreads();
    m = fmaxf(fmaxf(red[0], red[1]), fmaxf(red[2], red[3]));
    float s = 0.f;
#pragma unroll
    for (int i = 0; i < 8; i++) {
        v[i].x = __expf(v[i].x - m);
        v[i].y = __expf(v[i].y - m);
        v[i].z = __expf(v[i].z - m);
        v[i].w = __expf(v[i].w - m);
        s += v[i].x + v[i].y + v[i].z + v[i].w;
    }
#pragma unroll
    for (int off = 32; off > 0; off >>= 1) s += __shfl_xor(s, off);
    if ((t & 63) == 0) red[4 + (t >> 6)] = s;
    __syncthreads();
    s = red[4] + red[5] + red[6] + red[7];
    float inv = 1.f / s;
#pragma unroll
    for (int i = 0; i < 8; i++) {
        v[i].x *= inv; v[i].y *= inv; v[i].z *= inv; v[i].w *= inv;
        rp[i * 256 + t] = v[i];
    }
}

__global__ __launch_bounds__(256) void diag_kernel(const float* __restrict__ alpha,
                                                   float* __restrict__ da) {
    int i = blockIdx.x * 256 + threadIdx.x;
    da[i] = alpha[(size_t)i * N + i];
}

__global__ __launch_bounds__(256) void combine_kernel(const float* __restrict__ S,
                                                      const float* __restrict__ T,
                                                      const float* __restrict__ da,
                                                      const float* __restrict__ H,
                                                      const float* __restrict__ Dp,
                                                      float* __restrict__ hagg,
                                                      float* __restrict__ dagg) {
    int gid = blockIdx.x * 256 + threadIdx.x;
    int i = gid >> 6;
    int d4 = (gid & 63) * 4;
    float a = da[i];
    float4 sH = *f4c(S + (size_t)i * (2 * D) + d4);
    float4 sD = *f4c(S + (size_t)i * (2 * D) + D + d4);
    float4 tH = *f4c(T + (size_t)i * (2 * D) + d4);
    float4 tD = *f4c(T + (size_t)i * (2 * D) + D + d4);
    float4 h = *f4c(H + (size_t)i * D + d4);
    float4 dp = *f4c(Dp + (size_t)i * D + d4);
    float4 hd = {h.x + dp.x, h.y + dp.y, h.z + dp.z, h.w + dp.w};
    float4 ha = {tH.x + sD.x - a * hd.x, tH.y + sD.y - a * hd.y,
                 tH.z + sD.z - a * hd.z, tH.w + sD.w - a * hd.w};
    float4 dg = {sH.x + tD.x - a * hd.x, sH.y + tD.y - a * hd.y,
                 sH.z + tD.z - a * hd.z, sH.w + tD.w - a * hd.w};
    *f4(hagg + (size_t)i * D + d4) = ha;
    *f4(dagg + (size_t)i * D + d4) = dg;
}

extern "C" void kernel_launch(void* const* d_in, const int* in_sizes, int n_in,
                              void* d_out, int out_size, void* d_ws, size_t ws_size,
                              hipStream_t stream) {
    const float* head = (const float*)d_in[0];
    const float* dep = (const float*)d_in[1];
    const float* tpA[2] = {(const float*)d_in[2], (const float*)d_in[5]};
    const float* tpb1[2] = {(const float*)d_in[3], (const float*)d_in[6]};
    const float* tpb2[2] = {(const float*)d_in[4], (const float*)d_in[7]};
    const float* awh[2] = {(const float*)d_in[8], (const float*)d_in[12]};
    const float* awd[2] = {(const float*)d_in[9], (const float*)d_in[13]};
    const float* cwh[2] = {(const float*)d_in[10], (const float*)d_in[14]};
    const float* cwd[2] = {(const float*)d_in[11], (const float*)d_in[15]};

    float* out = (float*)d_out;
    float* outHead = out;
    float* outDep = out + (size_t)N * D;
    float* alpha1 = out + (size_t)2 * N * D;
    float* alpha2 = alpha1 + (size_t)N * N;

    float* w = (float*)d_ws;
    float* S = w;               w += (size_t)N * 2 * D;
    float* Z = S;               // overlay, disjoint lifetime
    float* T = w;               w += (size_t)N * 2 * D;
    float* bh = w;              w += N;
    float* bd = w;              w += N;
    float* da = w;              w += N;
    float* hagg = w;            w += (size_t)N * D;
    float* dagg = w;            w += (size_t)N * D;
    float* H1 = w;              w += (size_t)N * D;
    float* D1 = w;              w += (size_t)N * D;
    unsigned short* aP = (unsigned short*)w;
    unsigned short* xP = aP + (size_t)3 * N * N;
    size_t needed = ((char*)(xP + (size_t)3 * 512 * N)) - (char*)d_ws;
    const bool use_planes = (ws_size >= needed);

    for (int L = 0; L < 2; L++) {
        const float* Hin = L ? H1 : head;
        const float* Din = L ? D1 : dep;
        float* Hout = L ? outHead : H1;
        float* Dout = L ? outDep : D1;
        float* alpha = L ? alpha2 : alpha1;

        rowdot_kernel<<<N / 4, 256, 0, stream>>>(Hin, tpb1[L], bh);
        rowdot_kernel<<<N / 4, 256, 0, stream>>>(Din, tpb2[L], bd);
        gemm_nk256_kernel<<<dim3(D / 64, N / 64), 256, 0, stream>>>(Hin, tpA[L], Z);
        logits_kernel<<<dim3(N / 128, N / 128), 256, 0, stream>>>(Z, Din, bh, bd, alpha);
        if (use_planes) {
            if (L == 0) {
                softmax_planes<3><<<N, 256, 0, stream>>>(alpha, aP);
                diag_kernel<<<N / 256, 256, 0, stream>>>(alpha, da);
                splitX_kernel<3><<<dim3(N / 64, 8), 256, 0, stream>>>(Hin, Din, xP);
                agg_planes<3><<<dim3(4, N / 128, 2), 256, 0, stream>>>(aP, xP, S, T);
            } else {
                softmax_planes<1><<<N, 256, 0, stream>>>(alpha, aP);
                diag_kernel<<<N / 256, 256, 0, stream>>>(alpha, da);
                splitX_kernel<1><<<dim3(N / 64, 8), 256, 0, stream>>>(Hin, Din, xP);
                agg_planes<1><<<dim3(4, N / 128, 2), 256, 0, stream>>>(aP, xP, S, T);
            }
        } else {
            softmax_kernel<<<N, 256, 0, stream>>>(alpha);
            diag_kernel<<<N / 256, 256, 0, stream>>>(alpha, da);
            if (L == 0) {
                agg_mfma<6, 0><<<dim3(4, N / 128), 256, 0, stream>>>(alpha, Hin, Din, S);
                agg_mfma<6, 1><<<dim3(4, N / 128), 256, 0, stream>>>(alpha, Hin, Din, T);
            } else {
                agg_mfma<1, 0><<<dim3(4, N / 128), 256, 0, stream>>>(alpha, Hin, Din, S);
                agg_mfma<1, 1><<<dim3(4, N / 128), 256, 0, stream>>>(alpha, Hin, Din, T);
            }
        }
        combine_kernel<<<(N * D / 4) / 256, 256, 0, stream>>>(S, T, da, Hin, Din, hagg, dagg);
        update_kernel<<<dim3(D / 64, N / 64), 256, 0, stream>>>(hagg, awh[L], Hin, cwh[L], Hout);
        update_kernel<<<dim3(D / 64, N / 64), 256, 0, stream>>>(dagg, awd[L], Din, cwd[L], Dout);
    }
}